// Round 13
// baseline (461.864 us; speedup 1.0000x reference)
//
#include <hip/hip_runtime.h>
#include <hip/hip_fp16.h>
#include <math.h>

#define NN 100000
#define NE 500000
#define NREL 3
#define F 128
#define SCAN_BLK 1024
#define NBLK ((NN + SCAN_BLK - 1) / SCAN_BLK)   // 98
#define CH 50000
#define NCH 2

// CSR build partitioning
#define RANGE 16384
#define NRANGE 7            // 7*16384 >= NN
#define NPAD (NRANGE * RANGE)
#define EC 20
#define EPC (NE / EC)       // 25000

typedef __attribute__((ext_vector_type(8))) short bf16x8;
typedef __attribute__((ext_vector_type(4))) float f32x4;

__device__ __forceinline__ float sigm(float x) { return 1.f / (1.f + __expf(-x)); }

__device__ __forceinline__ unsigned bf16rne(float x) {
  unsigned u = __float_as_uint(x);
  return (u + 0x7FFFu + ((u >> 16) & 1u)) >> 16;
}
__device__ __forceinline__ void split1(float x, unsigned& h, unsigned& l) {
  h = bf16rne(x);
  float hf = __uint_as_float(h << 16);
  l = bf16rne(x - hf);
}

// LDS swizzles: 16B-slot XOR'd by row bits -> 2-way max on ds_read_b128
__device__ __forceinline__ int swz(int row, int slot) {     // row stride 32 u16
  return row * 32 + ((slot ^ ((row >> 1) & 3)) << 3);
}
__device__ __forceinline__ int swz64(int row, int slot) {   // row stride 64 u16
  return row * 64 + ((slot ^ ((row >> 1) & 7)) << 3);
}

// ---- atomic-free histogram, u16-PACKED LDS; XCD-grouped decode ----
__global__ __launch_bounds__(256) void hist_part(const int* __restrict__ src,
                                                 const int* __restrict__ dst,
                                                 ushort* __restrict__ part) {
  int x = blockIdx.x & 7, q = blockIdx.x >> 3;
  int g = q % NRANGE;
  int rc2 = x + 8 * (q / NRANGE);
  int a = rc2 / (NREL * EC);
  int rcl = rc2 % (NREL * EC);
  int r = rcl / EC, c = rcl % EC;
  __shared__ unsigned h32[RANGE / 2];   // 32 KB
  for (int i = threadIdx.x; i < RANGE / 2; i += 256) h32[i] = 0;
  __syncthreads();
  const int* idx = (a ? dst : src) + (size_t)r * NE + (size_t)c * EPC;
  const int4* v4 = (const int4*)idx;
  int lo = g * RANGE;
  for (int i = threadIdx.x; i < EPC / 4; i += 256) {
    int4 v = v4[i];
    int t;
    t = v.x - lo; if ((unsigned)t < RANGE) atomicAdd(&h32[t >> 1], 1u << ((t & 1) * 16));
    t = v.y - lo; if ((unsigned)t < RANGE) atomicAdd(&h32[t >> 1], 1u << ((t & 1) * 16));
    t = v.z - lo; if ((unsigned)t < RANGE) atomicAdd(&h32[t >> 1], 1u << ((t & 1) * 16));
    t = v.w - lo; if ((unsigned)t < RANGE) atomicAdd(&h32[t >> 1], 1u << ((t & 1) * 16));
  }
  __syncthreads();
  unsigned* op = (unsigned*)(part + (((size_t)a * NREL + r) * EC + c) * NPAD + (size_t)g * RANGE);
  for (int i = threadIdx.x; i < RANGE / 2; i += 256) op[i] = h32[i];
}

// fused: cnt_in + both rsqrt normalizers from u16 partials
__global__ void reduce_rs(const ushort* __restrict__ part, int* __restrict__ cnt_in,
                          float* __restrict__ rs_out, float* __restrict__ rs_in3) {
  int i = blockIdx.x * blockDim.x + threadIdx.x;
  if (i >= NREL * NN) return;
  int r = i / NN, node = i - r * NN;
  const ushort* p0 = part + ((size_t)r * EC) * NPAD + node;
  const ushort* p1 = part + (((size_t)NREL + r) * EC) * NPAD + node;
  int s0 = 0, s1 = 0;
#pragma unroll
  for (int c = 0; c < EC; ++c) {
    s0 += p0[(size_t)c * NPAD];
    s1 += p1[(size_t)c * NPAD];
  }
  cnt_in[i] = s1;
  rs_out[i] = rsqrtf((float)(s0 < 1 ? 1 : s0));
  rs_in3[i] = rsqrtf((float)(s1 < 1 ? 1 : s1)) * (1.f / 3.f);
}

// ---- two-level exclusive scan of cnt_in -> row_ptr ----
__global__ __launch_bounds__(256) void scan1(const int* __restrict__ cnt,
                                             int* __restrict__ excl, int* __restrict__ bsums) {
  int rb = blockIdx.x;
  int r = rb / NBLK, blk = rb % NBLK;
  int tid = (int)threadIdx.x;
  int v[4]; int sum = 0;
#pragma unroll
  for (int i = 0; i < 4; ++i) {
    int idx = blk * SCAN_BLK + tid * 4 + i;
    int c = (idx < NN) ? cnt[r * NN + idx] : 0;
    v[i] = sum; sum += c;
  }
  __shared__ int ts[256];
  ts[tid] = sum;
  __syncthreads();
  for (int off = 1; off < 256; off <<= 1) {
    int t = (tid >= off) ? ts[tid - off] : 0;
    __syncthreads();
    ts[tid] += t;
    __syncthreads();
  }
  int texcl = tid ? ts[tid - 1] : 0;
#pragma unroll
  for (int i = 0; i < 4; ++i) {
    int idx = blk * SCAN_BLK + tid * 4 + i;
    if (idx < NN) excl[r * NN + idx] = texcl + v[i];
  }
  if (tid == 255) bsums[rb] = ts[255];
}

__global__ __launch_bounds__(128) void scan2(int* __restrict__ bsums) {
  int r = blockIdx.x;
  int tid = (int)threadIdx.x;
  __shared__ int ts[128];
  ts[tid] = (tid < NBLK) ? bsums[r * NBLK + tid] : 0;
  __syncthreads();
  for (int off = 1; off < 128; off <<= 1) {
    int t = (tid >= off) ? ts[tid - off] : 0;
    __syncthreads();
    ts[tid] += t;
    __syncthreads();
  }
  if (tid < NBLK) bsums[r * NBLK + tid] = tid ? ts[tid - 1] : 0;
}

// fused: finalize row_ptr and emit per-chunk int cursor bases cb
__global__ void scan3_chunk(int* __restrict__ row_ptr, const int* __restrict__ bsums,
                            const ushort* __restrict__ part, int* __restrict__ cb) {
  int i = blockIdx.x * blockDim.x + threadIdx.x;
  if (i >= NREL * NN) return;
  int r = i / NN, node = i - r * NN, blk = node / SCAN_BLK;
  int base = row_ptr[i] + bsums[r * NBLK + blk];
  row_ptr[i] = base;
  const ushort* p1 = part + (((size_t)NREL + r) * EC) * NPAD + node;
  int run = base;
#pragma unroll
  for (int c = 0; c < EC; ++c) {
    cb[((size_t)r * EC + c) * NPAD + node] = run;
    run += p1[(size_t)c * NPAD];
  }
}

__global__ void make_pay(const int* __restrict__ src, const float* __restrict__ rs_out,
                         int2* __restrict__ pay) {
  int i = blockIdx.x * blockDim.x + threadIdx.x;
  if (i >= NREL * NE) return;
  int r = i / NE;
  int s = src[i];
  pay[i] = make_int2(s, __float_as_int(rs_out[r * NN + s]));
}

__global__ __launch_bounds__(256) void place_part(const int* __restrict__ dst,
                                                  const int2* __restrict__ pay,
                                                  const int* __restrict__ cb,
                                                  int2* __restrict__ ses) {
  int x = blockIdx.x & 7, q = blockIdx.x >> 3;
  int g = q % NRANGE;
  int rc = x + 8 * (q / NRANGE);
  if (rc >= NREL * EC) return;
  int r = rc / EC, c = rc % EC;
  __shared__ int cur[RANGE];
  const int* pc = cb + ((size_t)r * EC + c) * NPAD + (size_t)g * RANGE;
  for (int i = threadIdx.x; i < RANGE; i += 256) cur[i] = pc[i];
  __syncthreads();
  int lo = g * RANGE;
  const int4* d4 = (const int4*)(dst + (size_t)r * NE + (size_t)c * EPC);
  const int4* p4 = (const int4*)(pay + (size_t)r * NE + (size_t)c * EPC);
  int2* sesr = ses + (size_t)r * NE;
  for (int i = threadIdx.x; i < EPC / 4; i += 256) {
    int4 dv = d4[i];
    int4 pa = p4[2 * i], pb = p4[2 * i + 1];
    int t;
    t = dv.x - lo; if ((unsigned)t < RANGE) { int pos = atomicAdd(&cur[t], 1); sesr[pos] = make_int2(pa.x, pa.y); }
    t = dv.y - lo; if ((unsigned)t < RANGE) { int pos = atomicAdd(&cur[t], 1); sesr[pos] = make_int2(pa.z, pa.w); }
    t = dv.z - lo; if ((unsigned)t < RANGE) { int pos = atomicAdd(&cur[t], 1); sesr[pos] = make_int2(pb.x, pb.y); }
    t = dv.w - lo; if ((unsigned)t < RANGE) { int pos = atomicAdd(&cur[t], 1); sesr[pos] = make_int2(pb.z, pb.w); }
  }
}

// biases
__global__ void prep_small(const float* __restrict__ b1, const float* __restrict__ b2,
                           const float* __restrict__ bif, const float* __restrict__ bhf,
                           const float* __restrict__ bib, const float* __restrict__ bhb,
                           float* __restrict__ bbar1, float* __restrict__ bbar2,
                           float* __restrict__ bselw) {
  int t = (int)threadIdx.x;
  if (t < 128) {
    bbar1[t] = (b1[t] + b1[128 + t] + b1[256 + t]) * (1.f / 3.f);
  } else if (t < 256) {
    int j = t - 128;
    bbar2[j] = (b2[j] + b2[128 + j] + b2[256 + j]) * (1.f / 3.f);
  } else if (t < 640) {
    int m = t - 256;
    int g = m >> 7, j = m & 127, dir = j >> 6, jj = j & 63;
    int grow = (g == 0) ? jj : (g == 1) ? (128 + jj) : (192 + jj);
    bselw[m] = dir ? (bib[grow] + bhb[grow]) : (bif[grow] + bhf[grow]);
  }
}

// W[384][128] (k-major) -> split-bf16 transposed planes WT[n][k]
__global__ void wt_split(const float* __restrict__ W, ushort* __restrict__ th,
                         ushort* __restrict__ tl) {
  int i = blockIdx.x * blockDim.x + threadIdx.x;
  if (i >= 128 * 384) return;
  int n = i / 384, k = i % 384;
  float v = W[(size_t)k * 128 + n];
  unsigned h, l; split1(v, h, l);
  th[i] = (ushort)h; tl[i] = (ushort)l;
}

// lstm gate weights, packed+split: Wp[m][k], m = g*128 + dir*64 + jj
__global__ void pack_w_split(const float* __restrict__ Wf, const float* __restrict__ Wb,
                             ushort* __restrict__ ph, ushort* __restrict__ pl) {
  int i = blockIdx.x * blockDim.x + threadIdx.x;
  if (i >= 384 * 128) return;
  int m = i / 128, k = i % 128;
  int g = m >> 7, j = m & 127, dir = j >> 6, jj = j & 63;
  int grow = (g == 0) ? jj : (g == 1) ? (128 + jj) : (192 + jj);
  float v = (dir ? Wb : Wf)[(size_t)grow * 128 + k];
  unsigned h, l; split1(v, h, l);
  ph[i] = (ushort)h; pl[i] = (ushort)l;
}

// f32 [NN,128] -> f16 table
__global__ void cvt_f16(const float* __restrict__ in, ushort* __restrict__ o16) {
  int i = blockIdx.x * blockDim.x + threadIdx.x;
  if (i >= NN * (F / 4)) return;
  float4 v = ((const float4*)in)[i];
  __half2 a = __floats2half2_rn(v.x, v.y);
  __half2 b = __floats2half2_rn(v.z, v.w);
  ((uint2*)o16)[i] = make_uint2(*(unsigned*)&a, *(unsigned*)&b);
}

// quad-row gather: one wave per (node, relation); 16-edge batches.
__global__ __launch_bounds__(256) void gather3(
    const ushort* __restrict__ table, const int2* __restrict__ ses,
    const int* __restrict__ row_ptr, const int* __restrict__ cnt,
    const float* __restrict__ rs_in3, ushort* __restrict__ z16, int n0) {
  int wid = (int)threadIdx.x >> 6, lane = (int)threadIdx.x & 63;
  int gw = blockIdx.x * 4 + wid;
  int r = gw / CH;
  int n = n0 + (gw - r * CH);
  int base = r * NN + n;
  int beg = row_ptr[base], c = cnt[base];
  const int2* el = ses + (size_t)r * NE + beg;
  int qw = lane >> 4, cl = lane & 15;
  const uint4* x4 = (const uint4*)table + cl;
  float acc[8] = {};

  int p = 0;
  while (p < c) {
    int rem = c - p; if (rem > 16) rem = 16;
    int2 es = make_int2(0, 0);
    if (lane < rem) es = el[p + lane];
    uint4 rw[4]; float scv[4];
#pragma unroll
    for (int j = 0; j < 4; ++j) {
      int e = 4 * j + qw;
      int idx = (e < rem) ? e : 0;
      int s = __shfl(es.x, idx);
      float sc = __int_as_float(__shfl(es.y, idx));
      if (e >= rem) sc = 0.f;
      if (4 * j < rem) {
        rw[j] = x4[(size_t)s * 16];
        scv[j] = sc;
      }
    }
#pragma unroll
    for (int j = 0; j < 4; ++j) {
      if (4 * j < rem) {
        float sc = scv[j];
        float2 f0 = __half22float2(*(__half2*)&rw[j].x);
        float2 f1 = __half22float2(*(__half2*)&rw[j].y);
        float2 f2 = __half22float2(*(__half2*)&rw[j].z);
        float2 f3 = __half22float2(*(__half2*)&rw[j].w);
        acc[0] = fmaf(f0.x, sc, acc[0]); acc[1] = fmaf(f0.y, sc, acc[1]);
        acc[2] = fmaf(f1.x, sc, acc[2]); acc[3] = fmaf(f1.y, sc, acc[3]);
        acc[4] = fmaf(f2.x, sc, acc[4]); acc[5] = fmaf(f2.y, sc, acc[5]);
        acc[6] = fmaf(f3.x, sc, acc[6]); acc[7] = fmaf(f3.y, sc, acc[7]);
      }
    }
    p += rem;
  }

#pragma unroll
  for (int q = 0; q < 8; ++q) {
    acc[q] += __shfl_xor(acc[q], 16);
    acc[q] += __shfl_xor(acc[q], 32);
  }
  if (qw == 0) {
    float ci = rs_in3[base];
    __half2 p0 = __floats2half2_rn(acc[0] * ci, acc[1] * ci);
    __half2 p1 = __floats2half2_rn(acc[2] * ci, acc[3] * ci);
    __half2 p2 = __floats2half2_rn(acc[4] * ci, acc[5] * ci);
    __half2 p3 = __floats2half2_rn(acc[6] * ci, acc[7] * ci);
    size_t zo = (size_t)(n - n0) * 384 + r * 128 + cl * 8;
    *(uint4*)(z16 + zo) = make_uint4(*(unsigned*)&p0, *(unsigned*)&p1,
                                     *(unsigned*)&p2, *(unsigned*)&p3);
  }
}

// f16x8 -> split bf16 hi/lo uint4s
__device__ __forceinline__ void cvt_split8(uint4 v, uint4& hv, uint4& lv) {
  float f[8];
  *(float2*)&f[0] = __half22float2(*(__half2*)&v.x);
  *(float2*)&f[2] = __half22float2(*(__half2*)&v.y);
  *(float2*)&f[4] = __half22float2(*(__half2*)&v.z);
  *(float2*)&f[6] = __half22float2(*(__half2*)&v.w);
  unsigned h[8], l[8];
#pragma unroll
  for (int q = 0; q < 8; ++q) split1(f[q], h[q], l[q]);
  hv = make_uint4(h[0] | (h[1] << 16), h[2] | (h[3] << 16),
                  h[4] | (h[5] << 16), h[6] | (h[7] << 16));
  lv = make_uint4(l[0] | (l[1] << 16), l[2] | (l[3] << 16),
                  l[4] | (l[5] << 16), l[6] | (l[7] << 16));
}

// layer-1 GEMM (BK=64): h1 = relu(Z(f16)@WT^T + bias), f16 out. 256 thr.
__global__ __launch_bounds__(256) void gemm_mfma1(
    const ushort* __restrict__ z16,
    const ushort* __restrict__ wth, const ushort* __restrict__ wtl,
    const float* __restrict__ bias, ushort* __restrict__ Hout, int n0) {
  __shared__ ushort Ash[64 * 64], Asl[64 * 64], Bsh[128 * 64], Bsl[128 * 64]; // 48 KB
  const int row0 = blockIdx.x * 64;
  const int t = (int)threadIdx.x;
  const int wn = t >> 6, l = t & 63, lr = l & 15, lk = l >> 4;
  f32x4 acc[4][2];
#pragma unroll
  for (int a = 0; a < 4; ++a)
#pragma unroll
    for (int b = 0; b < 2; ++b) acc[a][b] = (f32x4){0.f, 0.f, 0.f, 0.f};

  for (int kt = 0; kt < 6; ++kt) {
    __syncthreads();
#pragma unroll
    for (int i = 0; i < 2; ++i) {   // A: 64 rows x 64 k = 512 uint4
      int s = i * 256 + t;
      int rr = s >> 3, slot = s & 7;
      uint4 v = make_uint4(0, 0, 0, 0);
      if (row0 + rr < CH)
        v = *(const uint4*)(z16 + (size_t)(row0 + rr) * 384 + kt * 64 + slot * 8);
      uint4 hv, lv; cvt_split8(v, hv, lv);
      *(uint4*)&Ash[swz64(rr, slot)] = hv;
      *(uint4*)&Asl[swz64(rr, slot)] = lv;
    }
#pragma unroll
    for (int i = 0; i < 4; ++i) {   // B: 128 n x 64 k = 1024 uint4
      int s = i * 256 + t;
      int nn_ = s >> 3, slot = s & 7;
      size_t go = (size_t)nn_ * 384 + kt * 64 + slot * 8;
      *(uint4*)&Bsh[swz64(nn_, slot)] = *(const uint4*)(wth + go);
      *(uint4*)&Bsl[swz64(nn_, slot)] = *(const uint4*)(wtl + go);
    }
    __syncthreads();
#pragma unroll
    for (int ks = 0; ks < 2; ++ks) {
      bf16x8 ah[4], al[4], bh[2], bl[2];
#pragma unroll
      for (int mf = 0; mf < 4; ++mf) {
        int off = swz64(mf * 16 + lr, ks * 4 + lk);
        ah[mf] = *(const bf16x8*)&Ash[off];
        al[mf] = *(const bf16x8*)&Asl[off];
      }
#pragma unroll
      for (int f = 0; f < 2; ++f) {
        int off = swz64(wn * 32 + f * 16 + lr, ks * 4 + lk);
        bh[f] = *(const bf16x8*)&Bsh[off];
        bl[f] = *(const bf16x8*)&Bsl[off];
      }
#pragma unroll
      for (int mf = 0; mf < 4; ++mf)
#pragma unroll
        for (int f = 0; f < 2; ++f) {
          acc[mf][f] = __builtin_amdgcn_mfma_f32_16x16x32_bf16(ah[mf], bh[f], acc[mf][f], 0, 0, 0);
          acc[mf][f] = __builtin_amdgcn_mfma_f32_16x16x32_bf16(ah[mf], bl[f], acc[mf][f], 0, 0, 0);
          acc[mf][f] = __builtin_amdgcn_mfma_f32_16x16x32_bf16(al[mf], bh[f], acc[mf][f], 0, 0, 0);
        }
    }
  }
#pragma unroll
  for (int mf = 0; mf < 4; ++mf)
#pragma unroll
    for (int f = 0; f < 2; ++f) {
      int col = wn * 32 + f * 16 + lr;
      float bv = bias[col];
#pragma unroll
      for (int reg = 0; reg < 4; ++reg) {
        int row = row0 + mf * 16 + lk * 4 + reg;
        if (row < CH) {
          float v = fmaxf(acc[mf][f][reg] + bv, 0.f);
          __half hv = __float2half_rn(v);
          Hout[(size_t)(n0 + row) * 128 + col] = *(ushort*)&hv;
        }
      }
    }
}

// fused layer-2 GEMM (BK=64) + BiLSTM. 512 thr, BM=64.
__global__ __launch_bounds__(512) void gemm2_lstm(
    const ushort* __restrict__ z16,
    const ushort* __restrict__ wth, const ushort* __restrict__ wtl,
    const ushort* __restrict__ wph, const ushort* __restrict__ wpl,
    const float* __restrict__ bbar2, const float* __restrict__ bselw,
    float* __restrict__ out, int n0) {
  __shared__ ushort lds[40960];   // 80 KB
  ushort* A1h = lds;              // [0,4096)      phase 1 (BK=64)
  ushort* A1l = lds + 4096;       // [4096,8192)
  ushort* B1h = lds + 8192;       // [8192,16384)
  ushort* B1l = lds + 16384;      // [16384,24576)
  ushort* A2h = lds;              // [0,8192)      phase 2/3
  ushort* A2l = lds + 8192;       // [8192,16384)
  ushort* B3h = lds + 16384;      // [16384,28672)
  ushort* B3l = lds + 28672;      // [28672,40960)

  const int row0 = blockIdx.x * 64;
  const int t = (int)threadIdx.x;
  const int wid = t >> 6, l = t & 63, lr = l & 15, lk = l >> 4;

  // ---- phase 1: h2 = Z @ W2T, 8 waves x 16 cols, BK=64 ----
  f32x4 acc1[4];
#pragma unroll
  for (int a = 0; a < 4; ++a) acc1[a] = (f32x4){0.f, 0.f, 0.f, 0.f};

  for (int kt = 0; kt < 6; ++kt) {
    __syncthreads();
    {   // A: 64 rows x 64 k = 512 uint4, one per thread
      int rr = t >> 3, slot = t & 7;
      uint4 v = make_uint4(0, 0, 0, 0);
      if (row0 + rr < CH)
        v = *(const uint4*)(z16 + (size_t)(row0 + rr) * 384 + kt * 64 + slot * 8);
      uint4 hv, lv; cvt_split8(v, hv, lv);
      *(uint4*)&A1h[swz64(rr, slot)] = hv;
      *(uint4*)&A1l[swz64(rr, slot)] = lv;
    }
#pragma unroll
    for (int i = 0; i < 2; ++i) {   // B: 128 n x 64 k = 1024 uint4
      int s = i * 512 + t;
      int nn_ = s >> 3, slot = s & 7;
      size_t go = (size_t)nn_ * 384 + kt * 64 + slot * 8;
      *(uint4*)&B1h[swz64(nn_, slot)] = *(const uint4*)(wth + go);
      *(uint4*)&B1l[swz64(nn_, slot)] = *(const uint4*)(wtl + go);
    }
    __syncthreads();
#pragma unroll
    for (int ks = 0; ks < 2; ++ks) {
      bf16x8 ah[4], al[4];
#pragma unroll
      for (int mf = 0; mf < 4; ++mf) {
        int off = swz64(mf * 16 + lr, ks * 4 + lk);
        ah[mf] = *(const bf16x8*)&A1h[off];
        al[mf] = *(const bf16x8*)&A1l[off];
      }
      int offb = swz64(wid * 16 + lr, ks * 4 + lk);
      bf16x8 bh = *(const bf16x8*)&B1h[offb];
      bf16x8 bl = *(const bf16x8*)&B1l[offb];
#pragma unroll
      for (int mf = 0; mf < 4; ++mf) {
        acc1[mf] = __builtin_amdgcn_mfma_f32_16x16x32_bf16(ah[mf], bh, acc1[mf], 0, 0, 0);
        acc1[mf] = __builtin_amdgcn_mfma_f32_16x16x32_bf16(ah[mf], bl, acc1[mf], 0, 0, 0);
        acc1[mf] = __builtin_amdgcn_mfma_f32_16x16x32_bf16(al[mf], bh, acc1[mf], 0, 0, 0);
      }
    }
  }

  // ---- phase 2: h2 -> A2 split planes (swizzled [64][128]) ----
  __syncthreads();
  {
    int colc = wid * 16 + lr;
    float bb = bbar2[colc];
#pragma unroll
    for (int mf = 0; mf < 4; ++mf)
#pragma unroll
      for (int reg = 0; reg < 4; ++reg) {
        int rowc = mf * 16 + lk * 4 + reg;
        float v = acc1[mf][reg] + bb;
        unsigned h, lo2; split1(v, h, lo2);
        int sl2 = (colc >> 3) ^ (rowc & 7);
        int addr = rowc * 128 + (sl2 << 3) + (colc & 7);
        A2h[addr] = (ushort)h;
        A2l[addr] = (ushort)lo2;
      }
  }
  __syncthreads();

  // ---- phase 3: gates = h2 @ WpT ----
  const int wm = wid >> 2, wn3 = wid & 3;
  f32x4 acc3[2][6];
#pragma unroll
  for (int a = 0; a < 2; ++a)
#pragma unroll
    for (int b = 0; b < 6; ++b) acc3[a][b] = (f32x4){0.f, 0.f, 0.f, 0.f};

  for (int kt = 0; kt < 4; ++kt) {
    if (kt) __syncthreads();
#pragma unroll
    for (int i = 0; i < 3; ++i) {
      int s = i * 512 + t;
      int m = s >> 2, slot = s & 3;
      size_t go = (size_t)m * 128 + kt * 32 + slot * 8;
      *(uint4*)&B3h[swz(m, slot)] = *(const uint4*)(wph + go);
      *(uint4*)&B3l[swz(m, slot)] = *(const uint4*)(wpl + go);
    }
    __syncthreads();
    bf16x8 ah2[2], al2[2];
#pragma unroll
    for (int mf = 0; mf < 2; ++mf) {
      int row = wm * 32 + mf * 16 + lr;
      int kslot = kt * 4 + lk;
      int sl2 = kslot ^ (row & 7);
      int addr = row * 128 + (sl2 << 3);
      ah2[mf] = *(const bf16x8*)&A2h[addr];
      al2[mf] = *(const bf16x8*)&A2l[addr];
    }
#pragma unroll
    for (int tt = 0; tt < 6; ++tt) {
      int m = (wn3 + 4 * tt) * 16 + lr;
      int off = swz(m, lk);
      bf16x8 bh = *(const bf16x8*)&B3h[off];
      bf16x8 bl = *(const bf16x8*)&B3l[off];
#pragma unroll
      for (int mf = 0; mf < 2; ++mf) {
        acc3[mf][tt] = __builtin_amdgcn_mfma_f32_16x16x32_bf16(ah2[mf], bh, acc3[mf][tt], 0, 0, 0);
        acc3[mf][tt] = __builtin_amdgcn_mfma_f32_16x16x32_bf16(ah2[mf], bl, acc3[mf][tt], 0, 0, 0);
        acc3[mf][tt] = __builtin_amdgcn_mfma_f32_16x16x32_bf16(al2[mf], bh, acc3[mf][tt], 0, 0, 0);
      }
    }
  }

  // ---- epilogue: LSTM activations ----
  int j0 = wn3 * 16 + lr, j1 = j0 + 64;
  float bi0 = bselw[j0], bg0 = bselw[128 + j0], bo0 = bselw[256 + j0];
  float bi1 = bselw[j1], bg1 = bselw[128 + j1], bo1 = bselw[256 + j1];
#pragma unroll
  for (int mf = 0; mf < 2; ++mf)
#pragma unroll
    for (int reg = 0; reg < 4; ++reg) {
      int grow = wm * 32 + mf * 16 + lk * 4 + reg;
      if (row0 + grow < CH) {
        size_t orow = (size_t)(n0 + row0 + grow) * 128;
        float iv0 = acc3[mf][0][reg] + bi0, gv0 = acc3[mf][2][reg] + bg0,
              ov0 = acc3[mf][4][reg] + bo0;
        float c0 = sigm(iv0) * tanhf(gv0);
        out[orow + j0] = sigm(ov0) * tanhf(c0);
        float iv1 = acc3[mf][1][reg] + bi1, gv1 = acc3[mf][3][reg] + bg1,
              ov1 = acc3[mf][5][reg] + bo1;
        float c1 = sigm(iv1) * tanhf(gv1);
        out[orow + j1] = sigm(ov1) * tanhf(c1);
      }
    }
}

extern "C" void kernel_launch(void* const* d_in, const int* in_sizes, int n_in,
                              void* d_out, int out_size, void* d_ws, size_t ws_size,
                              hipStream_t stream) {
  const float* x = (const float*)d_in[0];
  const int* src = (const int*)d_in[1];
  const int* dst = (const int*)d_in[2];
  const float* W1 = (const float*)d_in[3];
  const float* b1 = (const float*)d_in[4];
  const float* W2 = (const float*)d_in[5];
  const float* b2 = (const float*)d_in[6];
  const float* Wih_f = (const float*)d_in[7];
  const float* bih_f = (const float*)d_in[9];
  const float* bhh_f = (const float*)d_in[10];
  const float* Wih_b = (const float*)d_in[11];
  const float* bih_b = (const float*)d_in[13];
  const float* bhh_b = (const float*)d_in[14];
  float* out = (float*)d_out;

  // workspace carve-up (~107 MB)
  char* wp = (char*)d_ws;
  float* rs_out = (float*)wp;          wp += (size_t)3 * NN * 4;
  float* rs_in3 = (float*)wp;          wp += (size_t)3 * NN * 4;
  int* cnt_in = (int*)wp;              wp += (size_t)3 * NN * 4;
  int* row_ptr = (int*)wp;             wp += (size_t)3 * NN * 4;
  int* bsums = (int*)wp;               wp += 4096;
  int2* ses = (int2*)wp;               wp += (size_t)3 * NE * 8;
  ushort* wt1h = (ushort*)wp;          wp += (size_t)128 * 384 * 2;
  ushort* wt1l = (ushort*)wp;          wp += (size_t)128 * 384 * 2;
  ushort* wt2h = (ushort*)wp;          wp += (size_t)128 * 384 * 2;
  ushort* wt2l = (ushort*)wp;          wp += (size_t)128 * 384 * 2;
  ushort* wph = (ushort*)wp;           wp += (size_t)384 * 128 * 2;
  ushort* wpl = (ushort*)wp;           wp += (size_t)384 * 128 * 2;
  float* bbar1 = (float*)wp;           wp += 512;
  float* bbar2 = (float*)wp;           wp += 512;
  float* bselw = (float*)wp;           wp += 2048;
  ushort* z16 = (ushort*)wp;           wp += (size_t)CH * 384 * 2;   // 38.4 MB
  ushort* x16 = (ushort*)wp;           wp += (size_t)NN * F * 2;     // 25.6 MB
  ushort* h116 = (ushort*)wp;          wp += (size_t)NN * F * 2;     // 25.6 MB

  // CSR-build aliases (dead before z16/x16/h116 first use):
  ushort* part = (ushort*)z16;
  int* cb = (int*)((char*)z16 + ((size_t)28 << 20));
  int2* pay = (int2*)((char*)h116 + ((size_t)12 << 20));

  // CSR build — zero global atomics, XCD-grouped L2 reuse, u16 partials
  hist_part<<<2 * NREL * EC * NRANGE, 256, 0, stream>>>(src, dst, part);
  reduce_rs<<<(NREL * NN + 255) / 256, 256, 0, stream>>>(part, cnt_in, rs_out, rs_in3);
  scan1<<<NREL * NBLK, 256, 0, stream>>>(cnt_in, row_ptr, bsums);
  scan2<<<NREL, 128, 0, stream>>>(bsums);
  scan3_chunk<<<(NREL * NN + 255) / 256, 256, 0, stream>>>(row_ptr, bsums, part, cb);
  make_pay<<<(NREL * NE + 255) / 256, 256, 0, stream>>>(src, rs_out, pay);
  place_part<<<8 * ((NREL * EC + 7) / 8) * NRANGE, 256, 0, stream>>>(dst, pay, cb, ses);

  // weight prep
  prep_small<<<1, 640, 0, stream>>>(b1, b2, bih_f, bhh_f, bih_b, bhh_b, bbar1, bbar2, bselw);
  wt_split<<<192, 256, 0, stream>>>(W1, wt1h, wt1l);
  wt_split<<<192, 256, 0, stream>>>(W2, wt2h, wt2l);
  pack_w_split<<<192, 256, 0, stream>>>(Wih_f, Wih_b, wph, wpl);
  cvt_f16<<<(NN * 32 + 255) / 256, 256, 0, stream>>>(x, x16);

  // layer 1: x16 -> h116 (relu, f16)
  for (int c = 0; c < NCH; ++c) {
    gather3<<<3 * CH / 4, 256, 0, stream>>>(x16, ses, row_ptr, cnt_in, rs_in3, z16, c * CH);
    gemm_mfma1<<<(CH + 63) / 64, 256, 0, stream>>>(z16, wt1h, wt1l, bbar1, h116, c * CH);
  }
  // layer 2 + fused BiLSTM: h116 -> d_out
  for (int c = 0; c < NCH; ++c) {
    gather3<<<3 * CH / 4, 256, 0, stream>>>(h116, ses, row_ptr, cnt_in, rs_in3, z16, c * CH);
    gemm2_lstm<<<(CH + 63) / 64, 512, 0, stream>>>(z16, wt2h, wt2l, wph, wpl,
                                                   bbar2, bselw, out, c * CH);
  }
}

// Round 15
// 459.197 us; speedup vs baseline: 1.0058x; 1.0058x over previous
//
#include <hip/hip_runtime.h>
#include <hip/hip_fp16.h>
#include <math.h>

#define NN 100000
#define NE 500000
#define NREL 3
#define F 128
#define SCAN_BLK 1024
#define NBLK ((NN + SCAN_BLK - 1) / SCAN_BLK)   // 98
#define CH 50000
#define NCH 2

// CSR build partitioning
#define RANGE 16384
#define NRANGE 7            // 7*16384 >= NN
#define NPAD (NRANGE * RANGE)
#define EC 20
#define EPC (NE / EC)       // 25000

typedef __attribute__((ext_vector_type(8))) short bf16x8;
typedef __attribute__((ext_vector_type(4))) float f32x4;

__device__ __forceinline__ float sigm(float x) { return 1.f / (1.f + __expf(-x)); }

__device__ __forceinline__ unsigned bf16rne(float x) {
  unsigned u = __float_as_uint(x);
  return (u + 0x7FFFu + ((u >> 16) & 1u)) >> 16;
}
__device__ __forceinline__ void split1(float x, unsigned& h, unsigned& l) {
  h = bf16rne(x);
  float hf = __uint_as_float(h << 16);
  l = bf16rne(x - hf);
}

// LDS swizzle (row stride 32 ushorts): 2-way max on ds_read_b128
__device__ __forceinline__ int swz(int row, int slot) {
  return row * 32 + ((slot ^ ((row >> 1) & 3)) << 3);
}

// ---- atomic-free histogram, u16-PACKED LDS (32 KB -> ~2x occupancy).
// one block owns (array, rel, chunk, range); XCD-grouped decode.
// per-chunk per-node count <= EPC=25000 < 65536 -> low half never carries.
__global__ __launch_bounds__(256) void hist_part(const int* __restrict__ src,
                                                 const int* __restrict__ dst,
                                                 ushort* __restrict__ part) {
  int x = blockIdx.x & 7, q = blockIdx.x >> 3;
  int g = q % NRANGE;
  int rc2 = x + 8 * (q / NRANGE);
  int a = rc2 / (NREL * EC);
  int rcl = rc2 % (NREL * EC);
  int r = rcl / EC, c = rcl % EC;
  __shared__ unsigned h32[RANGE / 2];   // 32 KB
  for (int i = threadIdx.x; i < RANGE / 2; i += 256) h32[i] = 0;
  __syncthreads();
  const int* idx = (a ? dst : src) + (size_t)r * NE + (size_t)c * EPC;
  const int4* v4 = (const int4*)idx;
  int lo = g * RANGE;
  for (int i = threadIdx.x; i < EPC / 4; i += 256) {
    int4 v = v4[i];
    int t;
    t = v.x - lo; if ((unsigned)t < RANGE) atomicAdd(&h32[t >> 1], 1u << ((t & 1) * 16));
    t = v.y - lo; if ((unsigned)t < RANGE) atomicAdd(&h32[t >> 1], 1u << ((t & 1) * 16));
    t = v.z - lo; if ((unsigned)t < RANGE) atomicAdd(&h32[t >> 1], 1u << ((t & 1) * 16));
    t = v.w - lo; if ((unsigned)t < RANGE) atomicAdd(&h32[t >> 1], 1u << ((t & 1) * 16));
  }
  __syncthreads();
  // packed u32 layout == two consecutive u16 counts: copy directly
  unsigned* op = (unsigned*)(part + (((size_t)a * NREL + r) * EC + c) * NPAD + (size_t)g * RANGE);
  for (int i = threadIdx.x; i < RANGE / 2; i += 256) op[i] = h32[i];
}

// fused: cnt_in + both rsqrt normalizers from u16 partials
__global__ void reduce_rs(const ushort* __restrict__ part, int* __restrict__ cnt_in,
                          float* __restrict__ rs_out, float* __restrict__ rs_in3) {
  int i = blockIdx.x * blockDim.x + threadIdx.x;
  if (i >= NREL * NN) return;
  int r = i / NN, node = i - r * NN;
  const ushort* p0 = part + ((size_t)r * EC) * NPAD + node;
  const ushort* p1 = part + (((size_t)NREL + r) * EC) * NPAD + node;
  int s0 = 0, s1 = 0;
#pragma unroll
  for (int c = 0; c < EC; ++c) {
    s0 += p0[(size_t)c * NPAD];
    s1 += p1[(size_t)c * NPAD];
  }
  cnt_in[i] = s1;
  rs_out[i] = rsqrtf((float)(s0 < 1 ? 1 : s0));
  rs_in3[i] = rsqrtf((float)(s1 < 1 ? 1 : s1)) * (1.f / 3.f);
}

// ---- two-level exclusive scan of cnt_in -> row_ptr ----
__global__ __launch_bounds__(256) void scan1(const int* __restrict__ cnt,
                                             int* __restrict__ excl, int* __restrict__ bsums) {
  int rb = blockIdx.x;
  int r = rb / NBLK, blk = rb % NBLK;
  int tid = (int)threadIdx.x;
  int v[4]; int sum = 0;
#pragma unroll
  for (int i = 0; i < 4; ++i) {
    int idx = blk * SCAN_BLK + tid * 4 + i;
    int c = (idx < NN) ? cnt[r * NN + idx] : 0;
    v[i] = sum; sum += c;
  }
  __shared__ int ts[256];
  ts[tid] = sum;
  __syncthreads();
  for (int off = 1; off < 256; off <<= 1) {
    int t = (tid >= off) ? ts[tid - off] : 0;
    __syncthreads();
    ts[tid] += t;
    __syncthreads();
  }
  int texcl = tid ? ts[tid - 1] : 0;
#pragma unroll
  for (int i = 0; i < 4; ++i) {
    int idx = blk * SCAN_BLK + tid * 4 + i;
    if (idx < NN) excl[r * NN + idx] = texcl + v[i];
  }
  if (tid == 255) bsums[rb] = ts[255];
}

__global__ __launch_bounds__(128) void scan2(int* __restrict__ bsums) {
  int r = blockIdx.x;
  int tid = (int)threadIdx.x;
  __shared__ int ts[128];
  ts[tid] = (tid < NBLK) ? bsums[r * NBLK + tid] : 0;
  __syncthreads();
  for (int off = 1; off < 128; off <<= 1) {
    int t = (tid >= off) ? ts[tid - off] : 0;
    __syncthreads();
    ts[tid] += t;
    __syncthreads();
  }
  if (tid < NBLK) bsums[r * NBLK + tid] = tid ? ts[tid - 1] : 0;
}

// fused: finalize row_ptr and emit per-chunk int cursor bases cb
__global__ void scan3_chunk(int* __restrict__ row_ptr, const int* __restrict__ bsums,
                            const ushort* __restrict__ part, int* __restrict__ cb) {
  int i = blockIdx.x * blockDim.x + threadIdx.x;
  if (i >= NREL * NN) return;
  int r = i / NN, node = i - r * NN, blk = node / SCAN_BLK;
  int base = row_ptr[i] + bsums[r * NBLK + blk];
  row_ptr[i] = base;
  const ushort* p1 = part + (((size_t)NREL + r) * EC) * NPAD + node;
  int run = base;
#pragma unroll
  for (int c = 0; c < EC; ++c) {
    cb[((size_t)r * EC + c) * NPAD + node] = run;
    run += p1[(size_t)c * NPAD];
  }
}

__global__ void make_pay(const int* __restrict__ src, const float* __restrict__ rs_out,
                         int2* __restrict__ pay) {
  int i = blockIdx.x * blockDim.x + threadIdx.x;
  if (i >= NREL * NE) return;
  int r = i / NE;
  int s = src[i];
  pay[i] = make_int2(s, __float_as_int(rs_out[r * NN + s]));
}

__global__ __launch_bounds__(256) void place_part(const int* __restrict__ dst,
                                                  const int2* __restrict__ pay,
                                                  const int* __restrict__ cb,
                                                  int2* __restrict__ ses) {
  int x = blockIdx.x & 7, q = blockIdx.x >> 3;
  int g = q % NRANGE;
  int rc = x + 8 * (q / NRANGE);
  if (rc >= NREL * EC) return;
  int r = rc / EC, c = rc % EC;
  __shared__ int cur[RANGE];
  const int* pc = cb + ((size_t)r * EC + c) * NPAD + (size_t)g * RANGE;
  for (int i = threadIdx.x; i < RANGE; i += 256) cur[i] = pc[i];
  __syncthreads();
  int lo = g * RANGE;
  const int4* d4 = (const int4*)(dst + (size_t)r * NE + (size_t)c * EPC);
  const int4* p4 = (const int4*)(pay + (size_t)r * NE + (size_t)c * EPC);
  int2* sesr = ses + (size_t)r * NE;
  for (int i = threadIdx.x; i < EPC / 4; i += 256) {
    int4 dv = d4[i];
    int4 pa = p4[2 * i], pb = p4[2 * i + 1];
    int t;
    t = dv.x - lo; if ((unsigned)t < RANGE) { int pos = atomicAdd(&cur[t], 1); sesr[pos] = make_int2(pa.x, pa.y); }
    t = dv.y - lo; if ((unsigned)t < RANGE) { int pos = atomicAdd(&cur[t], 1); sesr[pos] = make_int2(pa.z, pa.w); }
    t = dv.z - lo; if ((unsigned)t < RANGE) { int pos = atomicAdd(&cur[t], 1); sesr[pos] = make_int2(pb.x, pb.y); }
    t = dv.w - lo; if ((unsigned)t < RANGE) { int pos = atomicAdd(&cur[t], 1); sesr[pos] = make_int2(pb.z, pb.w); }
  }
}

// biases
__global__ void prep_small(const float* __restrict__ b1, const float* __restrict__ b2,
                           const float* __restrict__ bif, const float* __restrict__ bhf,
                           const float* __restrict__ bib, const float* __restrict__ bhb,
                           float* __restrict__ bbar1, float* __restrict__ bbar2,
                           float* __restrict__ bselw) {
  int t = (int)threadIdx.x;
  if (t < 128) {
    bbar1[t] = (b1[t] + b1[128 + t] + b1[256 + t]) * (1.f / 3.f);
  } else if (t < 256) {
    int j = t - 128;
    bbar2[j] = (b2[j] + b2[128 + j] + b2[256 + j]) * (1.f / 3.f);
  } else if (t < 640) {
    int m = t - 256;
    int g = m >> 7, j = m & 127, dir = j >> 6, jj = j & 63;
    int grow = (g == 0) ? jj : (g == 1) ? (128 + jj) : (192 + jj);
    bselw[m] = dir ? (bib[grow] + bhb[grow]) : (bif[grow] + bhf[grow]);
  }
}

// W[384][128] (k-major) -> split-bf16 transposed planes WT[n][k]
__global__ void wt_split(const float* __restrict__ W, ushort* __restrict__ th,
                         ushort* __restrict__ tl) {
  int i = blockIdx.x * blockDim.x + threadIdx.x;
  if (i >= 128 * 384) return;
  int n = i / 384, k = i % 384;
  float v = W[(size_t)k * 128 + n];
  unsigned h, l; split1(v, h, l);
  th[i] = (ushort)h; tl[i] = (ushort)l;
}

// lstm gate weights, packed+split: Wp[m][k], m = g*128 + dir*64 + jj
__global__ void pack_w_split(const float* __restrict__ Wf, const float* __restrict__ Wb,
                             ushort* __restrict__ ph, ushort* __restrict__ pl) {
  int i = blockIdx.x * blockDim.x + threadIdx.x;
  if (i >= 384 * 128) return;
  int m = i / 128, k = i % 128;
  int g = m >> 7, j = m & 127, dir = j >> 6, jj = j & 63;
  int grow = (g == 0) ? jj : (g == 1) ? (128 + jj) : (192 + jj);
  float v = (dir ? Wb : Wf)[(size_t)grow * 128 + k];
  unsigned h, l; split1(v, h, l);
  ph[i] = (ushort)h; pl[i] = (ushort)l;
}

// f32 [NN,128] -> f16 table
__global__ void cvt_f16(const float* __restrict__ in, ushort* __restrict__ o16) {
  int i = blockIdx.x * blockDim.x + threadIdx.x;
  if (i >= NN * (F / 4)) return;
  float4 v = ((const float4*)in)[i];
  __half2 a = __floats2half2_rn(v.x, v.y);
  __half2 b = __floats2half2_rn(v.z, v.w);
  ((uint2*)o16)[i] = make_uint2(*(unsigned*)&a, *(unsigned*)&b);
}

// quad-row gather: one wave per (node, relation); 16-edge batches; per load
// instruction QUARTER-waves own 4 different edges (uint4 = 16 B/lane).
__global__ __launch_bounds__(256) void gather3(
    const ushort* __restrict__ table, const int2* __restrict__ ses,
    const int* __restrict__ row_ptr, const int* __restrict__ cnt,
    const float* __restrict__ rs_in3, ushort* __restrict__ z16, int n0) {
  int wid = (int)threadIdx.x >> 6, lane = (int)threadIdx.x & 63;
  int gw = blockIdx.x * 4 + wid;
  int r = gw / CH;
  int n = n0 + (gw - r * CH);
  int base = r * NN + n;
  int beg = row_ptr[base], c = cnt[base];
  const int2* el = ses + (size_t)r * NE + beg;
  int qw = lane >> 4, cl = lane & 15;          // cl owns cols cl*8 .. cl*8+7
  const uint4* x4 = (const uint4*)table + cl;  // row stride = 16 uint4 (256 B)
  float acc[8] = {};

  int p = 0;
  while (p < c) {
    int rem = c - p; if (rem > 16) rem = 16;
    int2 es = make_int2(0, 0);
    if (lane < rem) es = el[p + lane];
    uint4 rw[4]; float scv[4];
#pragma unroll
    for (int j = 0; j < 4; ++j) {
      int e = 4 * j + qw;
      int idx = (e < rem) ? e : 0;
      int s = __shfl(es.x, idx);
      float sc = __int_as_float(__shfl(es.y, idx));
      if (e >= rem) sc = 0.f;
      if (4 * j < rem) {            // wave-uniform guard
        rw[j] = x4[(size_t)s * 16];
        scv[j] = sc;
      }
    }
#pragma unroll
    for (int j = 0; j < 4; ++j) {
      if (4 * j < rem) {
        float sc = scv[j];
        float2 f0 = __half22float2(*(__half2*)&rw[j].x);
        float2 f1 = __half22float2(*(__half2*)&rw[j].y);
        float2 f2 = __half22float2(*(__half2*)&rw[j].z);
        float2 f3 = __half22float2(*(__half2*)&rw[j].w);
        acc[0] = fmaf(f0.x, sc, acc[0]); acc[1] = fmaf(f0.y, sc, acc[1]);
        acc[2] = fmaf(f1.x, sc, acc[2]); acc[3] = fmaf(f1.y, sc, acc[3]);
        acc[4] = fmaf(f2.x, sc, acc[4]); acc[5] = fmaf(f2.y, sc, acc[5]);
        acc[6] = fmaf(f3.x, sc, acc[6]); acc[7] = fmaf(f3.y, sc, acc[7]);
      }
    }
    p += rem;
  }

#pragma unroll
  for (int q = 0; q < 8; ++q) {
    acc[q] += __shfl_xor(acc[q], 16);
    acc[q] += __shfl_xor(acc[q], 32);
  }
  if (qw == 0) {
    float ci = rs_in3[base];
    __half2 p0 = __floats2half2_rn(acc[0] * ci, acc[1] * ci);
    __half2 p1 = __floats2half2_rn(acc[2] * ci, acc[3] * ci);
    __half2 p2 = __floats2half2_rn(acc[4] * ci, acc[5] * ci);
    __half2 p3 = __floats2half2_rn(acc[6] * ci, acc[7] * ci);
    size_t zo = (size_t)(n - n0) * 384 + r * 128 + cl * 8;
    *(uint4*)(z16 + zo) = make_uint4(*(unsigned*)&p0, *(unsigned*)&p1,
                                     *(unsigned*)&p2, *(unsigned*)&p3);
  }
}

// f16x8 -> split bf16 hi/lo uint4s
__device__ __forceinline__ void cvt_split8(uint4 v, uint4& hv, uint4& lv) {
  float f[8];
  *(float2*)&f[0] = __half22float2(*(__half2*)&v.x);
  *(float2*)&f[2] = __half22float2(*(__half2*)&v.y);
  *(float2*)&f[4] = __half22float2(*(__half2*)&v.z);
  *(float2*)&f[6] = __half22float2(*(__half2*)&v.w);
  unsigned h[8], l[8];
#pragma unroll
  for (int q = 0; q < 8; ++q) split1(f[q], h[q], l[q]);
  hv = make_uint4(h[0] | (h[1] << 16), h[2] | (h[3] << 16),
                  h[4] | (h[5] << 16), h[6] | (h[7] << 16));
  lv = make_uint4(l[0] | (l[1] << 16), l[2] | (l[3] << 16),
                  l[4] | (l[5] << 16), l[6] | (l[7] << 16));
}

// layer-1 GEMM: h1 = relu(Z(f16)[row,0:384] @ WT^T + bias), f16 out. 256 thr.
__global__ __launch_bounds__(256) void gemm_mfma1(
    const ushort* __restrict__ z16,
    const ushort* __restrict__ wth, const ushort* __restrict__ wtl,
    const float* __restrict__ bias, ushort* __restrict__ Hout, int n0) {
  __shared__ ushort Ash[64 * 32], Asl[64 * 32], Bsh[128 * 32], Bsl[128 * 32];
  const int row0 = blockIdx.x * 64;
  const int t = (int)threadIdx.x;
  const int wn = t >> 6, l = t & 63, lr = l & 15, lk = l >> 4;
  f32x4 acc[4][2];
#pragma unroll
  for (int a = 0; a < 4; ++a)
#pragma unroll
    for (int b = 0; b < 2; ++b) acc[a][b] = (f32x4){0.f, 0.f, 0.f, 0.f};

  for (int kt = 0; kt < 12; ++kt) {
    __syncthreads();
    {
      int rr = t >> 2, slot = t & 3;
      uint4 v = make_uint4(0, 0, 0, 0);
      if (row0 + rr < CH)
        v = *(const uint4*)(z16 + (size_t)(row0 + rr) * 384 + kt * 32 + slot * 8);
      uint4 hv, lv; cvt_split8(v, hv, lv);
      *(uint4*)&Ash[swz(rr, slot)] = hv;
      *(uint4*)&Asl[swz(rr, slot)] = lv;
    }
#pragma unroll
    for (int i = 0; i < 2; ++i) {
      int s = i * 256 + t;
      int nn_ = s >> 2, slot = s & 3;
      size_t go = (size_t)nn_ * 384 + kt * 32 + slot * 8;
      *(uint4*)&Bsh[swz(nn_, slot)] = *(const uint4*)(wth + go);
      *(uint4*)&Bsl[swz(nn_, slot)] = *(const uint4*)(wtl + go);
    }
    __syncthreads();
    bf16x8 ah[4], al[4], bh[2], bl[2];
#pragma unroll
    for (int mf = 0; mf < 4; ++mf) {
      int off = swz(mf * 16 + lr, lk);
      ah[mf] = *(const bf16x8*)&Ash[off];
      al[mf] = *(const bf16x8*)&Asl[off];
    }
#pragma unroll
    for (int f = 0; f < 2; ++f) {
      int off = swz(wn * 32 + f * 16 + lr, lk);
      bh[f] = *(const bf16x8*)&Bsh[off];
      bl[f] = *(const bf16x8*)&Bsl[off];
    }
#pragma unroll
    for (int mf = 0; mf < 4; ++mf)
#pragma unroll
      for (int f = 0; f < 2; ++f) {
        acc[mf][f] = __builtin_amdgcn_mfma_f32_16x16x32_bf16(ah[mf], bh[f], acc[mf][f], 0, 0, 0);
        acc[mf][f] = __builtin_amdgcn_mfma_f32_16x16x32_bf16(ah[mf], bl[f], acc[mf][f], 0, 0, 0);
        acc[mf][f] = __builtin_amdgcn_mfma_f32_16x16x32_bf16(al[mf], bh[f], acc[mf][f], 0, 0, 0);
      }
  }
#pragma unroll
  for (int mf = 0; mf < 4; ++mf)
#pragma unroll
    for (int f = 0; f < 2; ++f) {
      int col = wn * 32 + f * 16 + lr;
      float bv = bias[col];
#pragma unroll
      for (int reg = 0; reg < 4; ++reg) {
        int row = row0 + mf * 16 + lk * 4 + reg;
        if (row < CH) {
          float v = fmaxf(acc[mf][f][reg] + bv, 0.f);
          __half hv = __float2half_rn(v);
          Hout[(size_t)(n0 + row) * 128 + col] = *(ushort*)&hv;
        }
      }
    }
}

// fused layer-2 GEMM + BiLSTM. 512 thr, BM=64.
__global__ __launch_bounds__(512) void gemm2_lstm(
    const ushort* __restrict__ z16,
    const ushort* __restrict__ wth, const ushort* __restrict__ wtl,
    const ushort* __restrict__ wph, const ushort* __restrict__ wpl,
    const float* __restrict__ bbar2, const float* __restrict__ bselw,
    float* __restrict__ out, int n0) {
  __shared__ ushort lds[40960];   // 80 KB
  ushort* A1h = lds;
  ushort* A1l = lds + 2048;
  ushort* B1h = lds + 4096;
  ushort* B1l = lds + 8192;
  ushort* A2h = lds;
  ushort* A2l = lds + 8192;
  ushort* B3h = lds + 16384;
  ushort* B3l = lds + 28672;

  const int row0 = blockIdx.x * 64;
  const int t = (int)threadIdx.x;
  const int wid = t >> 6, l = t & 63, lr = l & 15, lk = l >> 4;

  f32x4 acc1[4];
#pragma unroll
  for (int a = 0; a < 4; ++a) acc1[a] = (f32x4){0.f, 0.f, 0.f, 0.f};

  for (int kt = 0; kt < 12; ++kt) {
    __syncthreads();
    if (t < 256) {
      int rr = t >> 2, slot = t & 3;
      uint4 v = make_uint4(0, 0, 0, 0);
      if (row0 + rr < CH)
        v = *(const uint4*)(z16 + (size_t)(row0 + rr) * 384 + kt * 32 + slot * 8);
      uint4 hv, lv; cvt_split8(v, hv, lv);
      *(uint4*)&A1h[swz(rr, slot)] = hv;
      *(uint4*)&A1l[swz(rr, slot)] = lv;
    }
    {
      int nn_ = t >> 2, slot = t & 3;
      size_t go = (size_t)nn_ * 384 + kt * 32 + slot * 8;
      *(uint4*)&B1h[swz(nn_, slot)] = *(const uint4*)(wth + go);
      *(uint4*)&B1l[swz(nn_, slot)] = *(const uint4*)(wtl + go);
    }
    __syncthreads();
    bf16x8 ah[4], al[4];
#pragma unroll
    for (int mf = 0; mf < 4; ++mf) {
      int off = swz(mf * 16 + lr, lk);
      ah[mf] = *(const bf16x8*)&A1h[off];
      al[mf] = *(const bf16x8*)&A1l[off];
    }
    int offb = swz(wid * 16 + lr, lk);
    bf16x8 bh = *(const bf16x8*)&B1h[offb];
    bf16x8 bl = *(const bf16x8*)&B1l[offb];
#pragma unroll
    for (int mf = 0; mf < 4; ++mf) {
      acc1[mf] = __builtin_amdgcn_mfma_f32_16x16x32_bf16(ah[mf], bh, acc1[mf], 0, 0, 0);
      acc1[mf] = __builtin_amdgcn_mfma_f32_16x16x32_bf16(ah[mf], bl, acc1[mf], 0, 0, 0);
      acc1[mf] = __builtin_amdgcn_mfma_f32_16x16x32_bf16(al[mf], bh, acc1[mf], 0, 0, 0);
    }
  }

  __syncthreads();
  {
    int colc = wid * 16 + lr;
    float bb = bbar2[colc];
#pragma unroll
    for (int mf = 0; mf < 4; ++mf)
#pragma unroll
      for (int reg = 0; reg < 4; ++reg) {
        int rowc = mf * 16 + lk * 4 + reg;
        float v = acc1[mf][reg] + bb;
        unsigned h, lo2; split1(v, h, lo2);
        int sl2 = (colc >> 3) ^ (rowc & 7);
        int addr = rowc * 128 + (sl2 << 3) + (colc & 7);
        A2h[addr] = (ushort)h;
        A2l[addr] = (ushort)lo2;
      }
  }
  __syncthreads();

  const int wm = wid >> 2, wn3 = wid & 3;
  f32x4 acc3[2][6];
#pragma unroll
  for (int a = 0; a < 2; ++a)
#pragma unroll
    for (int b = 0; b < 6; ++b) acc3[a][b] = (f32x4){0.f, 0.f, 0.f, 0.f};

  for (int kt = 0; kt < 4; ++kt) {
    if (kt) __syncthreads();
#pragma unroll
    for (int i = 0; i < 3; ++i) {
      int s = i * 512 + t;
      int m = s >> 2, slot = s & 3;
      size_t go = (size_t)m * 128 + kt * 32 + slot * 8;
      *(uint4*)&B3h[swz(m, slot)] = *(const uint4*)(wph + go);
      *(uint4*)&B3l[swz(m, slot)] = *(const uint4*)(wpl + go);
    }
    __syncthreads();
    bf16x8 ah2[2], al2[2];
#pragma unroll
    for (int mf = 0; mf < 2; ++mf) {
      int row = wm * 32 + mf * 16 + lr;
      int kslot = kt * 4 + lk;
      int sl2 = kslot ^ (row & 7);
      int addr = row * 128 + (sl2 << 3);
      ah2[mf] = *(const bf16x8*)&A2h[addr];
      al2[mf] = *(const bf16x8*)&A2l[addr];
    }
#pragma unroll
    for (int tt = 0; tt < 6; ++tt) {
      int m = (wn3 + 4 * tt) * 16 + lr;
      int off = swz(m, lk);
      bf16x8 bh = *(const bf16x8*)&B3h[off];
      bf16x8 bl = *(const bf16x8*)&B3l[off];
#pragma unroll
      for (int mf = 0; mf < 2; ++mf) {
        acc3[mf][tt] = __builtin_amdgcn_mfma_f32_16x16x32_bf16(ah2[mf], bh, acc3[mf][tt], 0, 0, 0);
        acc3[mf][tt] = __builtin_amdgcn_mfma_f32_16x16x32_bf16(ah2[mf], bl, acc3[mf][tt], 0, 0, 0);
        acc3[mf][tt] = __builtin_amdgcn_mfma_f32_16x16x32_bf16(al2[mf], bh, acc3[mf][tt], 0, 0, 0);
      }
    }
  }

  int j0 = wn3 * 16 + lr, j1 = j0 + 64;
  float bi0 = bselw[j0], bg0 = bselw[128 + j0], bo0 = bselw[256 + j0];
  float bi1 = bselw[j1], bg1 = bselw[128 + j1], bo1 = bselw[256 + j1];
#pragma unroll
  for (int mf = 0; mf < 2; ++mf)
#pragma unroll
    for (int reg = 0; reg < 4; ++reg) {
      int grow = wm * 32 + mf * 16 + lk * 4 + reg;
      if (row0 + grow < CH) {
        size_t orow = (size_t)(n0 + row0 + grow) * 128;
        float iv0 = acc3[mf][0][reg] + bi0, gv0 = acc3[mf][2][reg] + bg0,
              ov0 = acc3[mf][4][reg] + bo0;
        float c0 = sigm(iv0) * tanhf(gv0);
        out[orow + j0] = sigm(ov0) * tanhf(c0);
        float iv1 = acc3[mf][1][reg] + bi1, gv1 = acc3[mf][3][reg] + bg1,
              ov1 = acc3[mf][5][reg] + bo1;
        float c1 = sigm(iv1) * tanhf(gv1);
        out[orow + j1] = sigm(ov1) * tanhf(c1);
      }
    }
}

extern "C" void kernel_launch(void* const* d_in, const int* in_sizes, int n_in,
                              void* d_out, int out_size, void* d_ws, size_t ws_size,
                              hipStream_t stream) {
  const float* x = (const float*)d_in[0];
  const int* src = (const int*)d_in[1];
  const int* dst = (const int*)d_in[2];
  const float* W1 = (const float*)d_in[3];
  const float* b1 = (const float*)d_in[4];
  const float* W2 = (const float*)d_in[5];
  const float* b2 = (const float*)d_in[6];
  const float* Wih_f = (const float*)d_in[7];
  const float* bih_f = (const float*)d_in[9];
  const float* bhh_f = (const float*)d_in[10];
  const float* Wih_b = (const float*)d_in[11];
  const float* bih_b = (const float*)d_in[13];
  const float* bhh_b = (const float*)d_in[14];
  float* out = (float*)d_out;

  // workspace carve-up (~107 MB)
  char* wp = (char*)d_ws;
  float* rs_out = (float*)wp;          wp += (size_t)3 * NN * 4;
  float* rs_in3 = (float*)wp;          wp += (size_t)3 * NN * 4;
  int* cnt_in = (int*)wp;              wp += (size_t)3 * NN * 4;
  int* row_ptr = (int*)wp;             wp += (size_t)3 * NN * 4;
  int* bsums = (int*)wp;               wp += 4096;
  int2* ses = (int2*)wp;               wp += (size_t)3 * NE * 8;
  ushort* wt1h = (ushort*)wp;          wp += (size_t)128 * 384 * 2;
  ushort* wt1l = (ushort*)wp;          wp += (size_t)128 * 384 * 2;
  ushort* wt2h = (ushort*)wp;          wp += (size_t)128 * 384 * 2;
  ushort* wt2l = (ushort*)wp;          wp += (size_t)128 * 384 * 2;
  ushort* wph = (ushort*)wp;           wp += (size_t)384 * 128 * 2;
  ushort* wpl = (ushort*)wp;           wp += (size_t)384 * 128 * 2;
  float* bbar1 = (float*)wp;           wp += 512;
  float* bbar2 = (float*)wp;           wp += 512;
  float* bselw = (float*)wp;           wp += 2048;
  ushort* z16 = (ushort*)wp;           wp += (size_t)CH * 384 * 2;   // 38.4 MB
  ushort* x16 = (ushort*)wp;           wp += (size_t)NN * F * 2;     // 25.6 MB
  ushort* h116 = (ushort*)wp;          wp += (size_t)NN * F * 2;     // 25.6 MB

  // CSR-build aliases over the z16/x16/h116 region (89.6 MB), dead before use:
  // part (u16): 27.52 MB @ z16 (inside z16's 38.4 MB);
  // cb (int): 27.52 MB @ z16+28MB (ends 55.5MB < z16+x16 end 64MB; x16 written later);
  // pay: 12 MB @ h116+12MB (region offset 76MB, disjoint from cb's end).
  ushort* part = (ushort*)z16;
  int* cb = (int*)((char*)z16 + ((size_t)28 << 20));
  int2* pay = (int2*)((char*)h116 + ((size_t)12 << 20));

  // CSR build — zero global atomics, XCD-grouped L2 reuse, u16 partials
  hist_part<<<2 * NREL * EC * NRANGE, 256, 0, stream>>>(src, dst, part);
  reduce_rs<<<(NREL * NN + 255) / 256, 256, 0, stream>>>(part, cnt_in, rs_out, rs_in3);
  scan1<<<NREL * NBLK, 256, 0, stream>>>(cnt_in, row_ptr, bsums);
  scan2<<<NREL, 128, 0, stream>>>(bsums);
  scan3_chunk<<<(NREL * NN + 255) / 256, 256, 0, stream>>>(row_ptr, bsums, part, cb);
  make_pay<<<(NREL * NE + 255) / 256, 256, 0, stream>>>(src, rs_out, pay);
  place_part<<<8 * ((NREL * EC + 7) / 8) * NRANGE, 256, 0, stream>>>(dst, pay, cb, ses);

  // weight prep
  prep_small<<<1, 640, 0, stream>>>(b1, b2, bih_f, bhh_f, bih_b, bhh_b, bbar1, bbar2, bselw);
  wt_split<<<192, 256, 0, stream>>>(W1, wt1h, wt1l);
  wt_split<<<192, 256, 0, stream>>>(W2, wt2h, wt2l);
  pack_w_split<<<192, 256, 0, stream>>>(Wih_f, Wih_b, wph, wpl);
  cvt_f16<<<(NN * 32 + 255) / 256, 256, 0, stream>>>(x, x16);

  // layer 1: x16 -> h116 (relu, f16)
  for (int c = 0; c < NCH; ++c) {
    gather3<<<3 * CH / 4, 256, 0, stream>>>(x16, ses, row_ptr, cnt_in, rs_in3, z16, c * CH);
    gemm_mfma1<<<(CH + 63) / 64, 256, 0, stream>>>(z16, wt1h, wt1l, bbar1, h116, c * CH);
  }
  // layer 2 + fused BiLSTM: h116 -> d_out
  for (int c = 0; c < NCH; ++c) {
    gather3<<<3 * CH / 4, 256, 0, stream>>>(h116, ses, row_ptr, cnt_in, rs_in3, z16, c * CH);
    gemm2_lstm<<<(CH + 63) / 64, 512, 0, stream>>>(z16, wt2h, wt2l, wph, wpl,
                                                   bbar2, bselw, out, c * CH);
  }
}